// Round 12
// baseline (48.756 us; speedup 1.0000x reference)
//
#include <hip/hip_runtime.h>

#define NN 50000
#define NE 100000
#define NREL 64
#define D 64
#define RCAP 1280      // per-relation bucket capacity (expected ~676)
#define SCAP 8192      // self-only bucket capacity (expected ~6766)
#define CSTR 16        // cursor stride in ints (64 B per counter)
#define RB   8         // persistent blocks per relation
#define SB   64        // persistent blocks for self-only bucket
#define FILL_BLOCKS 128
#define FILL_ITERS  2

typedef unsigned long long u64;

// ws layout (bytes): packed [0,400000) | cursor @512K | rbucket @520K | sbucket @1M
#define WS_CURSOR  (512 * 1024)
#define WS_RBUCKET (520 * 1024)
#define WS_SBUCKET (1024 * 1024)

__global__ void k_init(u64* __restrict__ packed, int* __restrict__ cursor) {
    int t = blockIdx.x * blockDim.x + threadIdx.x;
    for (int i = t; i < NN; i += gridDim.x * blockDim.x) packed[i] = 0ull;
    if (t < 65) cursor[t * CSTR] = 0;
}

// one 64-bit atomicMax per edge: key = (e+1)<<22 | rel<<16 | src
__global__ void k_scatter(const int* __restrict__ edges, u64* __restrict__ packed) {
    int e = blockIdx.x * blockDim.x + threadIdx.x;
    if (e < NE) {
        int s = edges[e * 3 + 0];
        int r = edges[e * 3 + 1];
        int d = edges[e * 3 + 2];
        u64 key = ((u64)(e + 1) << 22) | ((u64)r << 16) | (u64)s;
        atomicMax(&packed[d], key);
    }
}

// block-aggregated bucket fill: LDS histogram -> 1 global atomic per (block, rel)
__global__ __launch_bounds__(256) void k_fill(
    const u64* __restrict__ packed, int* __restrict__ cursor,
    unsigned* __restrict__ rbucket, unsigned* __restrict__ sbucket)
{
    __shared__ int hcnt[65];
    __shared__ int hbase[65];
    const int t = threadIdx.x;
    if (t < 65) hcnt[t] = 0;
    __syncthreads();

    int      myr[FILL_ITERS];
    int      myslot[FILL_ITERS];
    unsigned myent[FILL_ITERS];

    #pragma unroll
    for (int it = 0; it < FILL_ITERS; ++it) {
        const int v = (blockIdx.x * FILL_ITERS + it) * 256 + t;
        myr[it] = -1;
        if (v < NN) {
            u64 key = packed[v];
            if (key) {
                myr[it]   = (int)((key >> 16) & 63);
                myent[it] = ((unsigned)v << 16) | (unsigned)(key & 0xFFFF);
            } else {
                myr[it]   = 64;
                myent[it] = (unsigned)v;
            }
            myslot[it] = atomicAdd(&hcnt[myr[it]], 1);
        }
    }
    __syncthreads();
    if (t < 65 && hcnt[t] > 0)
        hbase[t] = atomicAdd(&cursor[t * CSTR], hcnt[t]);
    __syncthreads();

    #pragma unroll
    for (int it = 0; it < FILL_ITERS; ++it) {
        const int r = myr[it];
        if (r >= 0) {
            const int p = hbase[r] + myslot[it];
            if (r < 64) { if (p < RCAP) rbucket[r * RCAP + p] = myent[it]; }
            else        { if (p < SCAP) sbucket[p] = myent[it]; }
        }
    }
}

__device__ __forceinline__ float elem(const float4& v, int k) {
    return (k == 0) ? v.x : (k == 1) ? v.y : (k == 2) ? v.z : v.w;
}

// lane = node; wave = 64 nodes x 16 output cols. Persistent blocks stride over
// their bucket's 64-node groups. Both matvecs fused into ONE i-loop and ONE
// accumulator: out = sum_i hs_i*W[i][o] + hv_i*WS[i][o].
__global__ __launch_bounds__(256) void k_compute(
    const float* __restrict__ h, const float* __restrict__ weight,
    const float* __restrict__ wself, const unsigned* __restrict__ rbucket,
    const unsigned* __restrict__ sbucket, const int* __restrict__ cursor,
    float* __restrict__ out)
{
    __shared__ float lds_w[D * D];   // W[r]    16 KiB
    __shared__ float lds_ws[D * D];  // W_self  16 KiB

    const int lane = threadIdx.x & 63;
    const int wv   = threadIdx.x >> 6;      // o-quarter 0..3
    const bool isRel = blockIdx.x < NREL * RB;

    int bslot, cnt, nstride, r = 0;
    const unsigned* __restrict__ seg;
    if (isRel) {
        r = blockIdx.x / RB;
        bslot = blockIdx.x % RB;
        nstride = RB;
        seg = rbucket + r * RCAP;
        cnt = min(cursor[r * CSTR], RCAP);
    } else {
        bslot = blockIdx.x - NREL * RB;
        nstride = SB;
        seg = sbucket;
        cnt = min(cursor[64 * CSTR], SCAP);
    }
    const int ngroups = (cnt + 63) >> 6;
    if (ngroups == 0) return;               // block-uniform, before any sync

    // ---- stage weights once per block ----
    if (isRel) {
        const float4* __restrict__ W4 = reinterpret_cast<const float4*>(weight + (size_t)r * D * D);
        #pragma unroll
        for (int k = 0; k < 4; ++k)
            reinterpret_cast<float4*>(lds_w)[k * 256 + threadIdx.x] = W4[k * 256 + threadIdx.x];
    }
    {
        const float4* __restrict__ WS4 = reinterpret_cast<const float4*>(wself);
        #pragma unroll
        for (int k = 0; k < 4; ++k)
            reinterpret_cast<float4*>(lds_ws)[k * 256 + threadIdx.x] = WS4[k * 256 + threadIdx.x];
    }
    __syncthreads();

    const int obase = wv * 16;

    for (int g = bslot; g < ngroups; g += nstride) {
        const unsigned ent = seg[min(g * 64 + lane, cnt - 1)];  // clamped tail: dup node, same value
        const int v = isRel ? (int)(ent >> 16) : (int)ent;
        const int s = (int)(ent & 0xFFFF);

        const float4* __restrict__ hv4 = reinterpret_cast<const float4*>(h + (size_t)v * D);
        const float4* __restrict__ hs4 = reinterpret_cast<const float4*>(h + (size_t)s * D);

        float acc[16];
        #pragma unroll
        for (int oo = 0; oo < 16; ++oo) acc[oo] = 0.f;

        if (isRel) {
            float4 hv[16], hs[16];
            #pragma unroll
            for (int k = 0; k < 16; ++k) hv[k] = hv4[k];
            #pragma unroll
            for (int k = 0; k < 16; ++k) hs[k] = hs4[k];

            #pragma unroll
            for (int i4 = 0; i4 < 16; ++i4) {
                #pragma unroll
                for (int ii = 0; ii < 4; ++ii) {
                    const int i = i4 * 4 + ii;
                    const float hbs = elem(hs[i4], ii);
                    const float hbv = elem(hv[i4], ii);
                    const float4* __restrict__ wr =
                        reinterpret_cast<const float4*>(&lds_w[i * D + obase]);   // uniform -> broadcast
                    const float4* __restrict__ wsr =
                        reinterpret_cast<const float4*>(&lds_ws[i * D + obase]);
                    #pragma unroll
                    for (int q = 0; q < 4; ++q) {
                        const float4 w  = wr[q];
                        const float4 ws = wsr[q];
                        acc[q * 4 + 0] = fmaf(hbs, w.x,  fmaf(hbv, ws.x, acc[q * 4 + 0]));
                        acc[q * 4 + 1] = fmaf(hbs, w.y,  fmaf(hbv, ws.y, acc[q * 4 + 1]));
                        acc[q * 4 + 2] = fmaf(hbs, w.z,  fmaf(hbv, ws.z, acc[q * 4 + 2]));
                        acc[q * 4 + 3] = fmaf(hbs, w.w,  fmaf(hbv, ws.w, acc[q * 4 + 3]));
                    }
                }
            }
        } else {
            float4 hv[16];
            #pragma unroll
            for (int k = 0; k < 16; ++k) hv[k] = hv4[k];

            #pragma unroll
            for (int i4 = 0; i4 < 16; ++i4) {
                #pragma unroll
                for (int ii = 0; ii < 4; ++ii) {
                    const int i = i4 * 4 + ii;
                    const float hbv = elem(hv[i4], ii);
                    const float4* __restrict__ wsr =
                        reinterpret_cast<const float4*>(&lds_ws[i * D + obase]);
                    #pragma unroll
                    for (int q = 0; q < 4; ++q) {
                        const float4 ws = wsr[q];
                        acc[q * 4 + 0] = fmaf(hbv, ws.x, acc[q * 4 + 0]);
                        acc[q * 4 + 1] = fmaf(hbv, ws.y, acc[q * 4 + 1]);
                        acc[q * 4 + 2] = fmaf(hbv, ws.z, acc[q * 4 + 2]);
                        acc[q * 4 + 3] = fmaf(hbv, ws.w, acc[q * 4 + 3]);
                    }
                }
            }
        }

        float4* __restrict__ orow = reinterpret_cast<float4*>(out + (size_t)v * D + obase);
        #pragma unroll
        for (int q = 0; q < 4; ++q)
            orow[q] = make_float4(acc[q * 4], acc[q * 4 + 1], acc[q * 4 + 2], acc[q * 4 + 3]);
    }
}

extern "C" void kernel_launch(void* const* d_in, const int* in_sizes, int n_in,
                              void* d_out, int out_size, void* d_ws, size_t ws_size,
                              hipStream_t stream) {
    const float* h      = (const float*)d_in[0];
    const int*   edges  = (const int*)d_in[1];
    const float* weight = (const float*)d_in[2];
    const float* wself  = (const float*)d_in[3];
    float* out = (float*)d_out;

    char* ws = (char*)d_ws;
    u64*      packed  = (u64*)ws;
    int*      cursor  = (int*)(ws + WS_CURSOR);
    unsigned* rbucket = (unsigned*)(ws + WS_RBUCKET);
    unsigned* sbucket = (unsigned*)(ws + WS_SBUCKET);

    k_init<<<128, 256, 0, stream>>>(packed, cursor);
    k_scatter<<<(NE + 255) / 256, 256, 0, stream>>>(edges, packed);
    k_fill<<<FILL_BLOCKS, 256, 0, stream>>>(packed, cursor, rbucket, sbucket);
    k_compute<<<NREL * RB + SB, 256, 0, stream>>>(h, weight, wself, rbucket, sbucket, cursor, out);
}